// Round 6
// baseline (19224.651 us; speedup 1.0000x reference)
//
#include <hip/hip_runtime.h>
#include <cstdint>
#include <cstddef>

#define S_LEN 512
#define TCH   128
#define NCH   4
#define HDIM  128
#define G4    512
#define BATCH 256
#define NLAYER 10

typedef float f32x4 __attribute__((ext_vector_type(4)));
typedef short short8 __attribute__((ext_vector_type(8)));

__device__ __forceinline__ float fsig(float x) {
  return __builtin_amdgcn_rcpf(1.0f + __expf(-x));
}
__device__ __forceinline__ float ftanh(float x) {
  return fmaf(2.0f, __builtin_amdgcn_rcpf(1.0f + __expf(-2.0f * x)), -1.0f);
}
__device__ __forceinline__ unsigned short bf16_rne(float x) {
  unsigned int u = __float_as_uint(x);
  unsigned int r = (u + 0x7fffu + ((u >> 16) & 1u)) >> 16;
  return (unsigned short)r;
}
__device__ __forceinline__ float bf16_to_f(unsigned short h) {
  return __uint_as_float(((unsigned int)h) << 16);
}

// ---------------------------------------------------------------------------
// Split fp32 weights into (hi, lo) bf16 pair: x ~= hi + lo.
// ---------------------------------------------------------------------------
__global__ void split_w(const float* __restrict__ W, unsigned short* __restrict__ hi,
                        unsigned short* __restrict__ lo, int n)
{
  int i = blockIdx.x * 256 + threadIdx.x;
  if (i < n) {
    float x = W[i];
    unsigned short h = bf16_rne(x);
    hi[i] = h;
    lo[i] = bf16_rne(x - bf16_to_f(h));
  }
}

// ---------------------------------------------------------------------------
// Layer-0 input GEMM (K=27), fp32 VALU. blockIdx.z = chunk (diag mode stages
// all 4 chunks in one launch; fallback passes t0base and grid.z=1).
// ---------------------------------------------------------------------------
template<int K>
__global__ __launch_bounds__(256, 4)
void gemm_xg_f32(const float* __restrict__ A, const float* __restrict__ W,
                 const float* __restrict__ bih, const float* __restrict__ bhh,
                 float* __restrict__ XGbase, size_t xgStride, int t0base)
{
  const int t0 = t0base + blockIdx.z * TCH;
  float* __restrict__ XG = XGbase + (size_t)blockIdx.z * xgStride;
  constexpr int BK  = (K < 64) ? K : 64;
  constexpr int NKC = K / BK;
  __shared__ float As[BK][68];
  __shared__ float Bs[BK][68];
  const int tid = threadIdx.x;
  const int tx = tid & 15;
  const int ty = tid >> 4;
  const int rowBase = blockIdx.x * 64;
  const int colBase = blockIdx.y * 64;
  float acc[4][4] = {{0.f,0.f,0.f,0.f},{0.f,0.f,0.f,0.f},{0.f,0.f,0.f,0.f},{0.f,0.f,0.f,0.f}};

  for (int kc = 0; kc < NKC; ++kc) {
    const int kbase = kc * BK;
    for (int idx = tid; idx < 64 * BK; idx += 256) {
      int rr = idx / BK;
      int k  = idx - rr * BK;
      int r  = rowBase + rr;
      int bb = r >> 7;
      int tt = r & (TCH - 1);
      As[k][rr] = A[(size_t)(bb * S_LEN + t0 + tt) * K + kbase + k];
    }
    for (int idx = tid; idx < 64 * BK; idx += 256) {
      int cc = idx / BK;
      int k  = idx - cc * BK;
      Bs[k][cc] = W[(size_t)(colBase + cc) * K + kbase + k];
    }
    __syncthreads();
    #pragma unroll 8
    for (int k = 0; k < BK; ++k) {
      const float4 av = *(const float4*)&As[k][ty * 4];
      const float4 bv = *(const float4*)&Bs[k][tx * 4];
      float a_[4] = {av.x, av.y, av.z, av.w};
      float b_[4] = {bv.x, bv.y, bv.z, bv.w};
      #pragma unroll
      for (int i = 0; i < 4; ++i) {
        #pragma unroll
        for (int jj = 0; jj < 4; ++jj)
          acc[i][jj] = fmaf(a_[i], b_[jj], acc[i][jj]);
      }
    }
    __syncthreads();
  }

  const int col0 = colBase + tx * 4;
  const float4 bi4 = *(const float4*)&bih[col0];
  const float4 bh4 = *(const float4*)&bhh[col0];
  const float b0 = bi4.x + bh4.x, b1 = bi4.y + bh4.y, b2 = bi4.z + bh4.z, b3 = bi4.w + bh4.w;
  #pragma unroll
  for (int i = 0; i < 4; ++i) {
    int r  = rowBase + ty * 4 + i;
    int bb = r >> 7;
    int tt = r & (TCH - 1);
    float4 o;
    o.x = acc[i][0] + b0; o.y = acc[i][1] + b1; o.z = acc[i][2] + b2; o.w = acc[i][3] + b3;
    *(float4*)&XG[(size_t)(bb * TCH + tt) * G4 + col0] = o;
  }
}

// ---------------------------------------------------------------------------
// Split-bf16 MFMA GEMM body. Round-5 version was L2-latency-bound on 40
// scattered 16B B-loads per wave; B is now cooperatively staged in LDS
// (coalesced), K in two 64-halves to stay under 64KB static LDS.
// ---------------------------------------------------------------------------
__device__ __forceinline__ void gemm_mfma_body(
    const float* __restrict__ A, const unsigned short* __restrict__ Whi,
    const unsigned short* __restrict__ Wlo,
    const float* __restrict__ bih, const float* __restrict__ bhh,
    float* __restrict__ XG, int t0,
    unsigned short (*Ahi)[136], unsigned short (*Alo)[136],
    unsigned short (*Bhi)[72], unsigned short (*Blo)[72])
{
  const int tid = threadIdx.x;
  const int rowBase = blockIdx.x * 64;
  const int colBase = blockIdx.y * 64;

  // Stage A: 64 rows x 128 k fp32 -> bf16 hi/lo in LDS.
  #pragma unroll
  for (int it = 0; it < 4; ++it) {
    int idx = tid + it * 256;
    int rr  = idx >> 4;
    int kg  = (idx & 15) * 8;
    int r   = rowBase + rr;
    int bb  = r >> 7;
    int tt  = r & (TCH - 1);
    const float* ap = &A[(size_t)(bb * S_LEN + t0 + tt) * HDIM + kg];
    float4 v0 = *(const float4*)ap;
    float4 v1 = *(const float4*)(ap + 4);
    float xs[8] = {v0.x, v0.y, v0.z, v0.w, v1.x, v1.y, v1.z, v1.w};
    unsigned short h[8], l8[8];
    #pragma unroll
    for (int j = 0; j < 8; ++j) {
      h[j]  = bf16_rne(xs[j]);
      l8[j] = bf16_rne(xs[j] - bf16_to_f(h[j]));
    }
    *(short8*)&Ahi[rr][kg] = *(short8*)h;
    *(short8*)&Alo[rr][kg] = *(short8*)l8;
  }

  const int w    = tid >> 6;
  const int ln   = tid & 63;
  const int fr   = ln & 15;
  const int kgrp = (ln >> 4) * 8;

  f32x4 acc[4] = {};
  #pragma unroll
  for (int kh = 0; kh < 2; ++kh) {
    __syncthreads();   // (kh=0: A visible; kh=1: prior B reads done)
    #pragma unroll
    for (int it = 0; it < 2; ++it) {
      int idx = tid + it * 256;
      int cc  = idx >> 3;
      int kg  = (idx & 7) * 8;
      *(short8*)&Bhi[cc][kg] = *(const short8*)&Whi[(size_t)(colBase + cc) * HDIM + kh * 64 + kg];
      *(short8*)&Blo[cc][kg] = *(const short8*)&Wlo[(size_t)(colBase + cc) * HDIM + kh * 64 + kg];
    }
    __syncthreads();
    #pragma unroll
    for (int ks = 0; ks < 2; ++ks) {
      const int k0 = kh * 64 + ks * 32 + kgrp;  // A LDS k-index
      const int kb = ks * 32 + kgrp;            // B LDS k-index
      short8 ah = *(const short8*)&Ahi[(w << 4) + fr][k0];
      short8 al = *(const short8*)&Alo[(w << 4) + fr][k0];
      #pragma unroll
      for (int nt = 0; nt < 4; ++nt) {
        short8 bh = *(const short8*)&Bhi[nt * 16 + fr][kb];
        short8 bl = *(const short8*)&Blo[nt * 16 + fr][kb];
        acc[nt] = __builtin_amdgcn_mfma_f32_16x16x32_bf16(ah, bh, acc[nt], 0, 0, 0);
        acc[nt] = __builtin_amdgcn_mfma_f32_16x16x32_bf16(ah, bl, acc[nt], 0, 0, 0);
        acc[nt] = __builtin_amdgcn_mfma_f32_16x16x32_bf16(al, bh, acc[nt], 0, 0, 0);
      }
    }
  }

  // Epilogue: C/D mapping col = lane&15, row = (lane>>4)*4 + reg.
  #pragma unroll
  for (int nt = 0; nt < 4; ++nt) {
    const int col = colBase + nt * 16 + fr;
    const float bsum = bih[col] + bhh[col];
    #pragma unroll
    for (int j = 0; j < 4; ++j) {
      int r  = rowBase + (w << 4) + ((ln >> 4) << 2) + j;
      int bb = r >> 7;
      int tt = r & (TCH - 1);
      XG[(size_t)(bb * TCH + tt) * G4 + col] = acc[nt][j] + bsum;
    }
  }
}

// Stage wrapper: blockIdx.z = pair p; l = lmin + p, c = s - l (l >= 1).
__global__ __launch_bounds__(256, 2)
void gemm_mfma_st(const float* __restrict__ H0, const float* __restrict__ H1,
                  const unsigned short* __restrict__ WhiAll,
                  const unsigned short* __restrict__ WloAll,
                  const float* __restrict__ bihAll, const float* __restrict__ bhhAll,
                  float* __restrict__ XGbase, size_t xgStride, int s, int lmin)
{
  __shared__ unsigned short Ahi[64][136];
  __shared__ unsigned short Alo[64][136];
  __shared__ unsigned short Bhi[64][72];
  __shared__ unsigned short Blo[64][72];
  const int l = lmin + blockIdx.z;
  const int c = s - l;
  const float* A = ((l - 1) & 1) ? H1 : H0;
  gemm_mfma_body(A,
                 WhiAll + (size_t)(l - 1) * G4 * HDIM,
                 WloAll + (size_t)(l - 1) * G4 * HDIM,
                 bihAll + l * G4, bhhAll + l * G4,
                 XGbase + (size_t)c * xgStride, c * TCH,
                 Ahi, Alo, Bhi, Blo);
}

// ---------------------------------------------------------------------------
// LSTM scan, diagonal-stage version. blockIdx = (batch b, pair p).
// l = lmin + p, c = s - l. 1024 threads; 2 blocks/CU co-resident (32 waves)
// so concurrent (l,c) pairs fill each other's barrier/LDS bubbles
// (round-4 single-block VALUBusy was ~45-49%).
// ---------------------------------------------------------------------------
__global__ __launch_bounds__(1024, 8)
void lstm_scan_st(const float* __restrict__ XGbase, size_t xgStride,
                  const float* __restrict__ WhhAll,
                  float* __restrict__ H0, float* __restrict__ H1,
                  float* __restrict__ cstAll, int s, int lmin)
{
  const int l  = lmin + blockIdx.y;
  const int c  = s - l;
  const int t0 = c * TCH;
  const float* __restrict__ XG  = XGbase + (size_t)c * xgStride;
  const float* __restrict__ Whh = WhhAll + (size_t)l * G4 * HDIM;
  float* __restrict__ Hout      = (l & 1) ? H1 : H0;
  float* __restrict__ c_state   = cstAll + (size_t)l * BATCH * HDIM;

  const int b   = blockIdx.x;
  const int tid = threadIdx.x;
  const int row = tid & 511;
  const int kh  = tid >> 9;
  __shared__ float h_s[2][HDIM];
  __shared__ float2 pp[G4];

  f32x4 w4[16];
  {
    const f32x4* wr = (const f32x4*)(Whh + (size_t)row * HDIM + kh * 64);
    #pragma unroll
    for (int kk = 0; kk < 16; ++kk) w4[kk] = wr[kk];
    #pragma unroll
    for (int kk = 0; kk < 16; ++kk) asm("" : "+v"(w4[kk]));  // opaque: no remat
  }

  float cacc = 0.0f;
  if (tid < HDIM) {
    if (t0 == 0) {
      h_s[0][tid] = 0.0f;
    } else {
      h_s[0][tid] = Hout[(size_t)(b * S_LEN + t0 - 1) * HDIM + tid];
      cacc = c_state[b * HDIM + tid];
    }
  }
  __syncthreads();

  const float* xgbase = XG + (size_t)b * TCH * G4;
  float xg_c = 0.f, xg_n = 0.f;
  if (kh == 0) {
    xg_c = xgbase[row];
    xg_n = xgbase[G4 + row];
  }

  for (int tt = 0; tt < TCH; ++tt) {
    const float xg = xg_c;
    xg_c = xg_n;
    if (kh == 0) {
      const int tn = (tt + 2 < TCH) ? (tt + 2) : (TCH - 1);
      xg_n = xgbase[(size_t)tn * G4 + row];
    }

    const f32x4* h4 = (const f32x4*)&h_s[tt & 1][kh * 64];
    float a0 = 0.f, a1 = 0.f, a2 = 0.f, a3 = 0.f;
    #pragma unroll
    for (int kk = 0; kk < 16; ++kk) {
      f32x4 hv = h4[kk];               // wave-uniform address -> LDS broadcast
      a0 = fmaf(w4[kk].x, hv.x, a0);
      a1 = fmaf(w4[kk].y, hv.y, a1);
      a2 = fmaf(w4[kk].z, hv.z, a2);
      a3 = fmaf(w4[kk].w, hv.w, a3);
    }
    const float p = (a0 + a1) + (a2 + a3);
    if (kh == 0) pp[row].x = p + xg;
    else         pp[row].y = p;
    __syncthreads();
    if (tid < HDIM) {
      float2 pi = pp[tid];
      float2 pf = pp[HDIM + tid];
      float2 pg = pp[2 * HDIM + tid];
      float2 po = pp[3 * HDIM + tid];
      float gi = fsig(pi.x + pi.y);
      float gf = fsig(pf.x + pf.y);
      float gg = ftanh(pg.x + pg.y);
      float go = fsig(po.x + po.y);
      cacc = fmaf(gf, cacc, gi * gg);
      float h = go * ftanh(cacc);
      h_s[(tt & 1) ^ 1][tid] = h;
      Hout[(size_t)(b * S_LEN + t0 + tt) * HDIM + tid] = h;
    }
    __syncthreads();
  }
  if (tid < HDIM) c_state[b * HDIM + tid] = cacc;
}

// ---------------------------------------------------------------------------
// Attention pass 1 (unchanged)
// ---------------------------------------------------------------------------
__global__ __launch_bounds__(128)
void attn1(const float* __restrict__ Hs, const float* __restrict__ attn_w,
           const float* __restrict__ attn_b, const float* __restrict__ v_w,
           const float* __restrict__ v_b, float* __restrict__ logits)
{
  const int b  = blockIdx.x;
  const int tc = blockIdx.y;
  const int j  = threadIdx.x;
  float wreg[HDIM];
  {
    const float4* wr = (const float4*)(attn_w + (size_t)j * HDIM);
    #pragma unroll
    for (int kk = 0; kk < 32; ++kk) {
      float4 v = wr[kk];
      wreg[4*kk+0] = v.x; wreg[4*kk+1] = v.y; wreg[4*kk+2] = v.z; wreg[4*kk+3] = v.w;
    }
  }
  const float ab = attn_b[j];
  const float vw = v_w[j];
  const float vb = v_b[0];
  __shared__ float outs[16][HDIM];
  __shared__ float red[2];
  for (int t8 = 0; t8 < 8; ++t8) {
    const int tbase = tc * 128 + t8 * 16;
    for (int idx = j; idx < 16 * HDIM; idx += 128) {
      int rr = idx >> 7;
      int k  = idx & 127;
      outs[rr][k] = Hs[(size_t)(b * S_LEN + tbase + rr) * HDIM + k];
    }
    __syncthreads();
    for (int rr = 0; rr < 16; ++rr) {
      const float4* o4 = (const float4*)outs[rr];
      float a0 = 0.f, a1 = 0.f, a2 = 0.f, a3 = 0.f;
      #pragma unroll
      for (int kk = 0; kk < 32; ++kk) {
        float4 hv = o4[kk];
        a0 = fmaf(wreg[4*kk+0], hv.x, a0);
        a1 = fmaf(wreg[4*kk+1], hv.y, a1);
        a2 = fmaf(wreg[4*kk+2], hv.z, a2);
        a3 = fmaf(wreg[4*kk+3], hv.w, a3);
      }
      float s = ftanh(((a0 + a1) + (a2 + a3)) + ab) * vw;
      #pragma unroll
      for (int off = 1; off < 64; off <<= 1) s += __shfl_xor(s, off);
      if ((j & 63) == 0) red[j >> 6] = s;
      __syncthreads();
      if (j == 0) logits[b * S_LEN + tbase + rr] = red[0] + red[1] + vb;
      __syncthreads();
    }
  }
}

// ---------------------------------------------------------------------------
// Attention pass 2 (unchanged)
// ---------------------------------------------------------------------------
__global__ __launch_bounds__(128)
void attn2(const float* __restrict__ Hs, const float* __restrict__ logits,
           const float* __restrict__ fc_w, const float* __restrict__ fc_b,
           float* __restrict__ outp)
{
  const int b   = blockIdx.x;
  const int tid = threadIdx.x;
  __shared__ float pbuf[S_LEN];
  __shared__ float red[4];
  __shared__ float ctx_s[HDIM];
  float l0 = logits[b * S_LEN + tid];
  float l1 = logits[b * S_LEN + 128 + tid];
  float l2 = logits[b * S_LEN + 256 + tid];
  float l3 = logits[b * S_LEN + 384 + tid];
  float m = fmaxf(fmaxf(l0, l1), fmaxf(l2, l3));
  #pragma unroll
  for (int off = 1; off < 64; off <<= 1) m = fmaxf(m, __shfl_xor(m, off));
  if ((tid & 63) == 0) red[tid >> 6] = m;
  __syncthreads();
  m = fmaxf(red[0], red[1]);
  float p0 = __expf(l0 - m), p1 = __expf(l1 - m), p2 = __expf(l2 - m), p3 = __expf(l3 - m);
  pbuf[tid] = p0; pbuf[tid + 128] = p1; pbuf[tid + 256] = p2; pbuf[tid + 384] = p3;
  float sum = (p0 + p1) + (p2 + p3);
  #pragma unroll
  for (int off = 1; off < 64; off <<= 1) sum += __shfl_xor(sum, off);
  if ((tid & 63) == 0) red[2 + (tid >> 6)] = sum;
  __syncthreads();
  const float sinv = 1.0f / (red[2] + red[3]);
  float acc = 0.f;
  const float* hp = Hs + (size_t)b * S_LEN * HDIM + tid;
  #pragma unroll 4
  for (int t = 0; t < S_LEN; ++t) acc = fmaf(pbuf[t], hp[(size_t)t * HDIM], acc);
  ctx_s[tid] = acc * sinv;
  __syncthreads();
  if (tid < 7) {
    float a = fc_b[tid];
    const float* fw = fc_w + tid * HDIM;
    #pragma unroll 8
    for (int k = 0; k < HDIM; ++k) a = fmaf(ctx_s[k], fw[k], a);
    outp[b * 7 + tid] = a;
  }
}

// ---------------------------------------------------------------------------
extern "C" void kernel_launch(void* const* d_in, const int* in_sizes, int n_in,
                              void* d_out, int out_size, void* d_ws, size_t ws_size,
                              hipStream_t stream)
{
  const float* x      = (const float*)d_in[0];
  const float* w_ih0  = (const float*)d_in[1];
  const float* w_ih   = (const float*)d_in[2];
  const float* w_hh   = (const float*)d_in[3];
  const float* b_ih   = (const float*)d_in[4];
  const float* b_hh   = (const float*)d_in[5];
  const float* attn_w = (const float*)d_in[6];
  const float* attn_b = (const float*)d_in[7];
  const float* v_w    = (const float*)d_in[8];
  const float* v_b    = (const float*)d_in[9];
  const float* fc_w   = (const float*)d_in[10];
  const float* fc_b   = (const float*)d_in[11];
  float* outp = (float*)d_out;

  const size_t szXGc = (size_t)BATCH * TCH * G4;   // floats per XG chunk buffer
  const size_t szH   = (size_t)BATCH * S_LEN * HDIM;
  const int    nWih  = (NLAYER - 1) * G4 * HDIM;

  const size_t need_diag =
      (4 * szXGc + 2 * szH + (size_t)NLAYER * BATCH * HDIM) * 4 + (size_t)nWih * 2 * 2;
  const size_t need_seq =
      (1 * szXGc + 2 * szH + (size_t)NLAYER * BATCH * HDIM) * 4 + (size_t)nWih * 2 * 2;
  const bool diag = (ws_size >= need_diag);
  if (!diag && ws_size < need_seq) return;  // ws too small: fail visibly

  char* p = (char*)d_ws;
  float* XG = (float*)p;  p += (diag ? 4 : 1) * szXGc * 4;
  float* H0 = (float*)p;  p += szH * 4;
  float* H1 = (float*)p;  p += szH * 4;
  float* cst = (float*)p; p += (size_t)NLAYER * BATCH * HDIM * 4;
  unsigned short* Whi = (unsigned short*)p; p += (size_t)nWih * 2;
  unsigned short* Wlo = (unsigned short*)p; p += (size_t)nWih * 2;
  float* lg = XG;                                   // XG dead before attention
  const size_t xgStride = diag ? szXGc : 0;

  split_w<<<(nWih + 255) / 256, 256, 0, stream>>>(w_ih, Whi, Wlo, nWih);

  if (diag) {
    // Layer-0 XG for all 4 chunks upfront (no dependencies).
    gemm_xg_f32<27><<<dim3(512, 8, 4), 256, 0, stream>>>(x, w_ih0, b_ih, b_hh, XG, xgStride, 0);
    // Wavefront stages: s = l + c, l in [0,10), c in [0,4).
    for (int s = 0; s <= NLAYER + NCH - 2; ++s) {
      int lmin = (s - (NCH - 1) > 0) ? s - (NCH - 1) : 0;
      int lmax = (s < NLAYER - 1) ? s : NLAYER - 1;
      lstm_scan_st<<<dim3(BATCH, lmax - lmin + 1), 1024, 0, stream>>>(
          XG, xgStride, w_hh, H0, H1, cst, s, lmin);
      int s2 = s + 1;
      int l2min = (s2 - (NCH - 1) > 1) ? s2 - (NCH - 1) : 1;
      int l2max = (s2 < NLAYER - 1) ? s2 : NLAYER - 1;
      if (l2min <= l2max)
        gemm_mfma_st<<<dim3(512, 8, l2max - l2min + 1), 256, 0, stream>>>(
            H0, H1, Whi, Wlo, b_ih, b_hh, XG, xgStride, s2, l2min);
    }
  } else {
    // Sequential fallback (round-5 structure with improved gemm).
    for (int l = 0; l < NLAYER; ++l) {
      for (int cch = 0; cch < NCH; ++cch) {
        if (l == 0)
          gemm_xg_f32<27><<<dim3(512, 8, 1), 256, 0, stream>>>(
              x, w_ih0, b_ih, b_hh, XG, 0, cch * TCH);
        else
          gemm_mfma_st<<<dim3(512, 8, 1), 256, 0, stream>>>(
              H0, H1, Whi, Wlo, b_ih, b_hh, XG, 0, l + cch, l);
        lstm_scan_st<<<dim3(BATCH, 1), 1024, 0, stream>>>(
            XG, 0, w_hh, H0, H1, cst, l + cch, l);
      }
    }
  }

  const float* Hlast = H1;  // layer 9 (odd) writes H1
  attn1<<<dim3(BATCH, 4), 128, 0, stream>>>(Hlast, attn_w, attn_b, v_w, v_b, lg);
  attn2<<<BATCH, 128, 0, stream>>>(Hlast, lg, fc_w, fc_b, outp);
}

// Round 7
// 11426.234 us; speedup vs baseline: 1.6825x; 1.6825x over previous
//
#include <hip/hip_runtime.h>
#include <cstdint>
#include <cstddef>

#define S_LEN 512
#define TCH   32
#define NCH   16
#define HDIM  128
#define G4    512
#define BATCH 256
#define NLAYER 10
#define ROWS  16              // batch rows per scan block
#define NBLK  (BATCH / ROWS)  // 16

typedef float f32x4 __attribute__((ext_vector_type(4)));
typedef short short8 __attribute__((ext_vector_type(8)));

__device__ __forceinline__ float fsig(float x) {
  return __builtin_amdgcn_rcpf(1.0f + __expf(-x));
}
__device__ __forceinline__ float ftanh(float x) {
  return fmaf(2.0f, __builtin_amdgcn_rcpf(1.0f + __expf(-2.0f * x)), -1.0f);
}
__device__ __forceinline__ unsigned short bf16_rne(float x) {
  unsigned int u = __float_as_uint(x);
  unsigned int r = (u + 0x7fffu + ((u >> 16) & 1u)) >> 16;
  return (unsigned short)r;
}
__device__ __forceinline__ float bf16_to_f(unsigned short h) {
  return __uint_as_float(((unsigned int)h) << 16);
}

// ---------------------------------------------------------------------------
// Split fp32 weights into (hi, lo) bf16 pair: x ~= hi + lo.
// ---------------------------------------------------------------------------
__global__ void split_w(const float* __restrict__ W, unsigned short* __restrict__ hi,
                        unsigned short* __restrict__ lo, int n)
{
  int i = blockIdx.x * 256 + threadIdx.x;
  if (i < n) {
    float x = W[i];
    unsigned short h = bf16_rne(x);
    hi[i] = h;
    lo[i] = bf16_rne(x - bf16_to_f(h));
  }
}

// ---------------------------------------------------------------------------
// Pre-arrange split Whh into MFMA B-fragment-linear order:
// WF[((l*16 + w)*16 + f)*512 + ln*8 + j], f = (ct<<3)|(ks<<1)|hl,
// holding W[col = w*32+ct*16+(ln&15)][k = ks*32+(ln>>4)*8 + j] (hi or lo).
// Scan waves then load their 16 frags as 16 coalesced b128 reads.
// ---------------------------------------------------------------------------
__global__ __launch_bounds__(256)
void whh_prep(const float* __restrict__ Whh, unsigned short* __restrict__ WF)
{
  int idx = blockIdx.x * 256 + threadIdx.x;   // [0, NLAYER*16*16*64)
  if (idx >= NLAYER * 16 * 16 * 64) return;
  int ln = idx & 63;
  int f  = (idx >> 6) & 15;
  int w  = (idx >> 10) & 15;
  int l  = idx >> 14;
  int ct = f >> 3, ks = (f >> 1) & 3, hl = f & 1;
  int col = w * 32 + ct * 16 + (ln & 15);
  int k0  = ks * 32 + (ln >> 4) * 8;
  const float* src = Whh + ((size_t)l * G4 + col) * HDIM + k0;
  unsigned short out[8];
  #pragma unroll
  for (int j = 0; j < 8; ++j) {
    float x = src[j];
    unsigned short h = bf16_rne(x);
    out[j] = hl ? bf16_rne(x - bf16_to_f(h)) : h;
  }
  *(short8*)&WF[(size_t)idx * 8] = *(short8*)out;
}

// ---------------------------------------------------------------------------
// Layer-0 input GEMM (K=27), fp32 VALU. blockIdx.z = chunk.
// ---------------------------------------------------------------------------
template<int K>
__global__ __launch_bounds__(256, 4)
void gemm_xg_f32(const float* __restrict__ A, const float* __restrict__ W,
                 const float* __restrict__ bih, const float* __restrict__ bhh,
                 float* __restrict__ XGbase, size_t xgStride, int t0base)
{
  const int t0 = t0base + blockIdx.z * TCH;
  float* __restrict__ XG = XGbase + (size_t)blockIdx.z * xgStride;
  constexpr int BK  = (K < 64) ? K : 64;
  constexpr int NKC = K / BK;
  __shared__ float As[BK][68];
  __shared__ float Bs[BK][68];
  const int tid = threadIdx.x;
  const int tx = tid & 15;
  const int ty = tid >> 4;
  const int rowBase = blockIdx.x * 64;
  const int colBase = blockIdx.y * 64;
  float acc[4][4] = {{0.f,0.f,0.f,0.f},{0.f,0.f,0.f,0.f},{0.f,0.f,0.f,0.f},{0.f,0.f,0.f,0.f}};

  for (int kc = 0; kc < NKC; ++kc) {
    const int kbase = kc * BK;
    for (int idx = tid; idx < 64 * BK; idx += 256) {
      int rr = idx / BK;
      int k  = idx - rr * BK;
      int r  = rowBase + rr;
      int bb = r / TCH;
      int tt = r - bb * TCH;
      As[k][rr] = A[(size_t)(bb * S_LEN + t0 + tt) * K + kbase + k];
    }
    for (int idx = tid; idx < 64 * BK; idx += 256) {
      int cc = idx / BK;
      int k  = idx - cc * BK;
      Bs[k][cc] = W[(size_t)(colBase + cc) * K + kbase + k];
    }
    __syncthreads();
    #pragma unroll 8
    for (int k = 0; k < BK; ++k) {
      const float4 av = *(const float4*)&As[k][ty * 4];
      const float4 bv = *(const float4*)&Bs[k][tx * 4];
      float a_[4] = {av.x, av.y, av.z, av.w};
      float b_[4] = {bv.x, bv.y, bv.z, bv.w};
      #pragma unroll
      for (int i = 0; i < 4; ++i) {
        #pragma unroll
        for (int jj = 0; jj < 4; ++jj)
          acc[i][jj] = fmaf(a_[i], b_[jj], acc[i][jj]);
      }
    }
    __syncthreads();
  }

  const int col0 = colBase + tx * 4;
  const float4 bi4 = *(const float4*)&bih[col0];
  const float4 bh4 = *(const float4*)&bhh[col0];
  const float b0 = bi4.x + bh4.x, b1 = bi4.y + bh4.y, b2 = bi4.z + bh4.z, b3 = bi4.w + bh4.w;
  #pragma unroll
  for (int i = 0; i < 4; ++i) {
    int r  = rowBase + ty * 4 + i;
    float4 o;
    o.x = acc[i][0] + b0; o.y = acc[i][1] + b1; o.z = acc[i][2] + b2; o.w = acc[i][3] + b3;
    *(float4*)&XG[(size_t)r * G4 + col0] = o;   // r == bb*TCH + tt
  }
}

// ---------------------------------------------------------------------------
// Split-bf16 MFMA input GEMM (layers 1..9). A converted in LDS; B staged in
// LDS coalesced (round-5 was L2-latency-bound on scattered B loads).
// ---------------------------------------------------------------------------
__device__ __forceinline__ void gemm_mfma_body(
    const float* __restrict__ A, const unsigned short* __restrict__ Whi,
    const unsigned short* __restrict__ Wlo,
    const float* __restrict__ bih, const float* __restrict__ bhh,
    float* __restrict__ XG, int t0,
    unsigned short (*Ahi)[136], unsigned short (*Alo)[136],
    unsigned short (*Bhi)[72], unsigned short (*Blo)[72])
{
  const int tid = threadIdx.x;
  const int rowBase = blockIdx.x * 64;
  const int colBase = blockIdx.y * 64;

  #pragma unroll
  for (int it = 0; it < 4; ++it) {
    int idx = tid + it * 256;
    int rr  = idx >> 4;
    int kg  = (idx & 15) * 8;
    int r   = rowBase + rr;
    int bb  = r / TCH;
    int tt  = r - bb * TCH;
    const float* ap = &A[(size_t)(bb * S_LEN + t0 + tt) * HDIM + kg];
    float4 v0 = *(const float4*)ap;
    float4 v1 = *(const float4*)(ap + 4);
    float xs[8] = {v0.x, v0.y, v0.z, v0.w, v1.x, v1.y, v1.z, v1.w};
    unsigned short h[8], l8[8];
    #pragma unroll
    for (int j = 0; j < 8; ++j) {
      h[j]  = bf16_rne(xs[j]);
      l8[j] = bf16_rne(xs[j] - bf16_to_f(h[j]));
    }
    *(short8*)&Ahi[rr][kg] = *(short8*)h;
    *(short8*)&Alo[rr][kg] = *(short8*)l8;
  }

  const int w    = tid >> 6;
  const int ln   = tid & 63;
  const int fr   = ln & 15;
  const int kgrp = (ln >> 4) * 8;

  f32x4 acc[4] = {};
  #pragma unroll
  for (int kh = 0; kh < 2; ++kh) {
    __syncthreads();
    #pragma unroll
    for (int it = 0; it < 2; ++it) {
      int idx = tid + it * 256;
      int cc  = idx >> 3;
      int kg  = (idx & 7) * 8;
      *(short8*)&Bhi[cc][kg] = *(const short8*)&Whi[(size_t)(colBase + cc) * HDIM + kh * 64 + kg];
      *(short8*)&Blo[cc][kg] = *(const short8*)&Wlo[(size_t)(colBase + cc) * HDIM + kh * 64 + kg];
    }
    __syncthreads();
    #pragma unroll
    for (int ks = 0; ks < 2; ++ks) {
      const int k0 = kh * 64 + ks * 32 + kgrp;
      const int kb = ks * 32 + kgrp;
      short8 ah = *(const short8*)&Ahi[(w << 4) + fr][k0];
      short8 al = *(const short8*)&Alo[(w << 4) + fr][k0];
      #pragma unroll
      for (int nt = 0; nt < 4; ++nt) {
        short8 bh = *(const short8*)&Bhi[nt * 16 + fr][kb];
        short8 bl = *(const short8*)&Blo[nt * 16 + fr][kb];
        acc[nt] = __builtin_amdgcn_mfma_f32_16x16x32_bf16(ah, bh, acc[nt], 0, 0, 0);
        acc[nt] = __builtin_amdgcn_mfma_f32_16x16x32_bf16(ah, bl, acc[nt], 0, 0, 0);
        acc[nt] = __builtin_amdgcn_mfma_f32_16x16x32_bf16(al, bh, acc[nt], 0, 0, 0);
      }
    }
  }

  #pragma unroll
  for (int nt = 0; nt < 4; ++nt) {
    const int col = colBase + nt * 16 + fr;
    const float bsum = bih[col] + bhh[col];
    #pragma unroll
    for (int j = 0; j < 4; ++j) {
      int r = rowBase + (w << 4) + ((ln >> 4) << 2) + j;
      XG[(size_t)r * G4 + col] = acc[nt][j] + bsum;
    }
  }
}

// Stage wrapper: blockIdx.z = pair p; l = lmin + p, c = s - l (l >= 1).
__global__ __launch_bounds__(256, 2)
void gemm_mfma_st(const float* __restrict__ H0, const float* __restrict__ H1,
                  const unsigned short* __restrict__ WhiAll,
                  const unsigned short* __restrict__ WloAll,
                  const float* __restrict__ bihAll, const float* __restrict__ bhhAll,
                  float* __restrict__ XGbase, size_t xgStride, int s, int lmin)
{
  __shared__ unsigned short Ahi[64][136];
  __shared__ unsigned short Alo[64][136];
  __shared__ unsigned short Bhi[64][72];
  __shared__ unsigned short Blo[64][72];
  const int l = lmin + blockIdx.z;
  const int c = s - l;
  const float* A = ((l - 1) & 1) ? H1 : H0;
  gemm_mfma_body(A,
                 WhiAll + (size_t)(l - 1) * G4 * HDIM,
                 WloAll + (size_t)(l - 1) * G4 * HDIM,
                 bihAll + l * G4, bhhAll + l * G4,
                 XGbase + (size_t)c * xgStride, c * TCH,
                 Ahi, Alo, Bhi, Blo);
}

// ---------------------------------------------------------------------------
// MFMA LSTM scan. Block = 16 batch rows of pair (l, ch); 1024 threads.
// Wave w owns gate cols [w*32, w*32+32); its Whh fragments (3-term split,
// 16 frags = 64 VGPRs) stay in registers, loaded coalesced from WF.
// h staged in LDS as bf16 hi/lo A-fragments, XOR-swizzled (^((row&7)<<4));
// pre-acts exchanged via swizzled pp; gates on all 1024 threads; c in regs.
// 2 barriers/step. VGPR budget ~115 < 128 cap of (1024,4)  [round-6 lesson:
// (1024,8) capped at 64 and spilled everything].
// ---------------------------------------------------------------------------
__global__ __launch_bounds__(1024, 4)
void scan_mfma(const float* __restrict__ XGbase, size_t xgStride,
               const unsigned short* __restrict__ WF,
               float* __restrict__ H0, float* __restrict__ H1,
               float* __restrict__ cstAll, int s, int lmin)
{
  const int l  = lmin + blockIdx.y;
  const int ch = s - l;
  const int t0 = ch * TCH;
  const float* __restrict__ XG = XGbase + (size_t)ch * xgStride;
  float* __restrict__ Hout = (l & 1) ? H1 : H0;
  float* __restrict__ cst  = cstAll + (size_t)l * BATCH * HDIM;
  const int B0  = blockIdx.x * ROWS;
  const int tid = threadIdx.x;
  const int w   = tid >> 6;
  const int ln  = tid & 63;
  const int lr  = ln & 15;
  const int lk  = ln >> 4;

  __shared__ unsigned short hA[2 * ROWS * HDIM];  // [hl][row][k], swizzled
  __shared__ float pp[ROWS * G4];                 // pre-acts, swizzled

  // --- B fragments into registers (16 coalesced b128 loads) ---
  short8 bf[16];
  {
    const unsigned short* wfp = WF + (((size_t)l * 16 + w) * 16) * 512 + (size_t)ln * 8;
    #pragma unroll
    for (int f = 0; f < 16; ++f) bf[f] = *(const short8*)(wfp + (size_t)f * 512);
    #pragma unroll
    for (int f = 0; f < 16; ++f) asm("" : "+v"(bf[f]));
  }

  // --- gate-thread mapping & initial h/c ---
  const int grow0 = tid >> 7;        // 0..7
  const int grow1 = grow0 + 8;
  const int ghid  = tid & 127;
  float c0 = 0.f, c1 = 0.f;
  {
    float h0v = 0.f, h1v = 0.f;
    if (t0 > 0) {
      h0v = Hout[((size_t)(B0 + grow0) * S_LEN + (t0 - 1)) * HDIM + ghid];
      h1v = Hout[((size_t)(B0 + grow1) * S_LEN + (t0 - 1)) * HDIM + ghid];
      c0 = cst[(B0 + grow0) * HDIM + ghid];
      c1 = cst[(B0 + grow1) * HDIM + ghid];
    }
    unsigned short hi0 = bf16_rne(h0v);
    unsigned short lo0 = bf16_rne(h0v - bf16_to_f(hi0));
    unsigned short hi1 = bf16_rne(h1v);
    unsigned short lo1 = bf16_rne(h1v - bf16_to_f(hi1));
    int by0 = (grow0 * 256 + ghid * 2) ^ ((grow0 & 7) << 4);
    int by1 = (grow1 * 256 + ghid * 2) ^ ((grow1 & 7) << 4);
    *(unsigned short*)((char*)hA + by0) = hi0;
    *(unsigned short*)((char*)hA + 4096 + by0) = lo0;
    *(unsigned short*)((char*)hA + by1) = hi1;
    *(unsigned short*)((char*)hA + 4096 + by1) = lo1;
  }
  __syncthreads();

  // xg base for this lane's (ct,j) outputs; advances by G4 per step
  const float* xgl = XG + (size_t)(B0 + lk * 4) * TCH * G4 + w * 32 + lr;
  float* hout0 = Hout + ((size_t)(B0 + grow0) * S_LEN + t0) * HDIM + ghid;
  float* hout1 = Hout + ((size_t)(B0 + grow1) * S_LEN + t0) * HDIM + ghid;

  for (int tt = 0; tt < TCH; ++tt) {
    // xg loads issued before MFMA; latency hides under MFMA + ds_reads
    float xgv[8];
    #pragma unroll
    for (int ct = 0; ct < 2; ++ct)
      #pragma unroll
      for (int j = 0; j < 4; ++j)
        xgv[ct * 4 + j] = xgl[(size_t)j * (TCH * G4) + ct * 16];

    f32x4 acc0 = {0.f, 0.f, 0.f, 0.f}, acc1 = {0.f, 0.f, 0.f, 0.f};
    #pragma unroll
    for (int ks = 0; ks < 4; ++ks) {
      const int by = (lr * 256 + ks * 64 + lk * 16) ^ ((lr & 7) << 4);
      short8 ah = *(const short8*)((const char*)hA + by);
      short8 al = *(const short8*)((const char*)hA + 4096 + by);
      acc0 = __builtin_amdgcn_mfma_f32_16x16x32_bf16(ah, bf[(ks << 1) | 0], acc0, 0, 0, 0);
      acc0 = __builtin_amdgcn_mfma_f32_16x16x32_bf16(ah, bf[(ks << 1) | 1], acc0, 0, 0, 0);
      acc0 = __builtin_amdgcn_mfma_f32_16x16x32_bf16(al, bf[(ks << 1) | 0], acc0, 0, 0, 0);
      acc1 = __builtin_amdgcn_mfma_f32_16x16x32_bf16(ah, bf[8 | (ks << 1) | 0], acc1, 0, 0, 0);
      acc1 = __builtin_amdgcn_mfma_f32_16x16x32_bf16(ah, bf[8 | (ks << 1) | 1], acc1, 0, 0, 0);
      acc1 = __builtin_amdgcn_mfma_f32_16x16x32_bf16(al, bf[8 | (ks << 1) | 0], acc1, 0, 0, 0);
    }

    // pre-acts -> pp (swizzled), xg folded in
    #pragma unroll
    for (int j = 0; j < 4; ++j) {
      int r16 = lk * 4 + j;
      int colA = w * 32 + lr;
      int byA = (r16 * 2048 + colA * 4) ^ ((r16 & 3) << 5);
      *(float*)((char*)pp + byA) = acc0[j] + xgv[j];
      int colB = colA + 16;
      int byB = (r16 * 2048 + colB * 4) ^ ((r16 & 3) << 5);
      *(float*)((char*)pp + byB) = acc1[j] + xgv[4 + j];
    }
    __syncthreads();

    // gate phase: 2 (row,hid) pairs per thread
    {
      int b0 = grow0 * 2048, x0 = (grow0 & 3) << 5;
      float pi = *(const float*)((const char*)pp + ((b0 + (ghid)            * 4) ^ x0));
      float pf = *(const float*)((const char*)pp + ((b0 + (128 + ghid)      * 4) ^ x0));
      float pg = *(const float*)((const char*)pp + ((b0 + (256 + ghid)      * 4) ^ x0));
      float po = *(const float*)((const char*)pp + ((b0 + (384 + ghid)      * 4) ^ x0));
      float gi = fsig(pi), gf = fsig(pf), gg = ftanh(pg), go = fsig(po);
      c0 = fmaf(gf, c0, gi * gg);
      float h0 = go * ftanh(c0);

      int b1 = grow1 * 2048, x1 = (grow1 & 3) << 5;
      float qi = *(const float*)((const char*)pp + ((b1 + (ghid)            * 4) ^ x1));
      float qf = *(const float*)((const char*)pp + ((b1 + (128 + ghid)      * 4) ^ x1));
      float qg = *(const float*)((const char*)pp + ((b1 + (256 + ghid)      * 4) ^ x1));
      float qo = *(const float*)((const char*)pp + ((b1 + (384 + ghid)      * 4) ^ x1));
      float hi_ = fsig(qi), hf = fsig(qf), hg = ftanh(qg), ho = fsig(qo);
      c1 = fmaf(hf, c1, hi_ * hg);
      float h1 = ho * ftanh(c1);

      hout0[0] = h0;
      hout1[0] = h1;
      unsigned short s0 = bf16_rne(h0);
      unsigned short t0b = bf16_rne(h0 - bf16_to_f(s0));
      unsigned short s1 = bf16_rne(h1);
      unsigned short t1b = bf16_rne(h1 - bf16_to_f(s1));
      int by0 = (grow0 * 256 + ghid * 2) ^ ((grow0 & 7) << 4);
      int by1 = (grow1 * 256 + ghid * 2) ^ ((grow1 & 7) << 4);
      *(unsigned short*)((char*)hA + by0) = s0;
      *(unsigned short*)((char*)hA + 4096 + by0) = t0b;
      *(unsigned short*)((char*)hA + by1) = s1;
      *(unsigned short*)((char*)hA + 4096 + by1) = t1b;
    }
    __syncthreads();
    xgl += G4;
    hout0 += HDIM;
    hout1 += HDIM;
  }
  cst[(B0 + grow0) * HDIM + ghid] = c0;
  cst[(B0 + grow1) * HDIM + ghid] = c1;
}

// ---------------------------------------------------------------------------
// Attention pass 1 (unchanged)
// ---------------------------------------------------------------------------
__global__ __launch_bounds__(128)
void attn1(const float* __restrict__ Hs, const float* __restrict__ attn_w,
           const float* __restrict__ attn_b, const float* __restrict__ v_w,
           const float* __restrict__ v_b, float* __restrict__ logits)
{
  const int b  = blockIdx.x;
  const int tc = blockIdx.y;
  const int j  = threadIdx.x;
  float wreg[HDIM];
  {
    const float4* wr = (const float4*)(attn_w + (size_t)j * HDIM);
    #pragma unroll
    for (int kk = 0; kk < 32; ++kk) {
      float4 v = wr[kk];
      wreg[4*kk+0] = v.x; wreg[4*kk+1] = v.y; wreg[4*kk+2] = v.z; wreg[4*kk+3] = v.w;
    }
  }
  const float ab = attn_b[j];
  const float vw = v_w[j];
  const float vb = v_b[0];
  __shared__ float outs[16][HDIM];
  __shared__ float red[2];
  for (int t8 = 0; t8 < 8; ++t8) {
    const int tbase = tc * 128 + t8 * 16;
    for (int idx = j; idx < 16 * HDIM; idx += 128) {
      int rr = idx >> 7;
      int k  = idx & 127;
      outs[rr][k] = Hs[(size_t)(b * S_LEN + tbase + rr) * HDIM + k];
    }
    __syncthreads();
    for (int rr = 0; rr < 16; ++rr) {
      const float4* o4 = (const float4*)outs[rr];
      float a0 = 0.f, a1 = 0.f, a2 = 0.f, a3 = 0.f;
      #pragma unroll
      for (int kk = 0; kk < 32; ++kk) {
        float4 hv = o4[kk];
        a0 = fmaf(wreg[4*kk+0], hv.x, a0);
        a1 = fmaf(wreg[4*kk+1], hv.y, a1);
        a2 = fmaf(wreg[4*kk+2], hv.z, a2);
        a3 = fmaf(wreg[4*kk+3], hv.w, a3);
      }
      float s = ftanh(((a0 + a1) + (a2 + a3)) + ab) * vw;
      #pragma unroll
      for (int off = 1; off < 64; off <<= 1) s += __shfl_xor(s, off);
      if ((j & 63) == 0) red[j >> 6] = s;
      __syncthreads();
      if (j == 0) logits[b * S_LEN + tbase + rr] = red[0] + red[1] + vb;
      __syncthreads();
    }
  }
}

// ---------------------------------------------------------------------------
// Attention pass 2 (unchanged)
// ---------------------------------------------------------------------------
__global__ __launch_bounds__(128)
void attn2(const float* __restrict__ Hs, const float* __restrict__ logits,
           const float* __restrict__ fc_w, const float* __restrict__ fc_b,
           float* __restrict__ outp)
{
  const int b   = blockIdx.x;
  const int tid = threadIdx.x;
  __shared__ float pbuf[S_LEN];
  __shared__ float red[4];
  __shared__ float ctx_s[HDIM];
  float l0 = logits[b * S_LEN + tid];
  float l1 = logits[b * S_LEN + 128 + tid];
  float l2 = logits[b * S_LEN + 256 + tid];
  float l3 = logits[b * S_LEN + 384 + tid];
  float m = fmaxf(fmaxf(l0, l1), fmaxf(l2, l3));
  #pragma unroll
  for (int off = 1; off < 64; off <<= 1) m = fmaxf(m, __shfl_xor(m, off));
  if ((tid & 63) == 0) red[tid >> 6] = m;
  __syncthreads();
  m = fmaxf(red[0], red[1]);
  float p0 = __expf(l0 - m), p1 = __expf(l1 - m), p2 = __expf(l2 - m), p3 = __expf(l3 - m);
  pbuf[tid] = p0; pbuf[tid + 128] = p1; pbuf[tid + 256] = p2; pbuf[tid + 384] = p3;
  float sum = (p0 + p1) + (p2 + p3);
  #pragma unroll
  for (int off = 1; off < 64; off <<= 1) sum += __shfl_xor(sum, off);
  if ((tid & 63) == 0) red[2 + (tid >> 6)] = sum;
  __syncthreads();
  const float sinv = 1.0f / (red[2] + red[3]);
  float acc = 0.f;
  const float* hp = Hs + (size_t)b * S_LEN * HDIM + tid;
  #pragma unroll 4
  for (int t = 0; t < S_LEN; ++t) acc = fmaf(pbuf[t], hp[(size_t)t * HDIM], acc);
  ctx_s[tid] = acc * sinv;
  __syncthreads();
  if (tid < 7) {
    float a = fc_b[tid];
    const float* fw = fc_w + tid * HDIM;
    #pragma unroll 8
    for (int k = 0; k < HDIM; ++k) a = fmaf(ctx_s[k], fw[k], a);
    outp[b * 7 + tid] = a;
  }
}

// ---------------------------------------------------------------------------
extern "C" void kernel_launch(void* const* d_in, const int* in_sizes, int n_in,
                              void* d_out, int out_size, void* d_ws, size_t ws_size,
                              hipStream_t stream)
{
  const float* x      = (const float*)d_in[0];
  const float* w_ih0  = (const float*)d_in[1];
  const float* w_ih   = (const float*)d_in[2];
  const float* w_hh   = (const float*)d_in[3];
  const float* b_ih   = (const float*)d_in[4];
  const float* b_hh   = (const float*)d_in[5];
  const float* attn_w = (const float*)d_in[6];
  const float* attn_b = (const float*)d_in[7];
  const float* v_w    = (const float*)d_in[8];
  const float* v_b    = (const float*)d_in[9];
  const float* fc_w   = (const float*)d_in[10];
  const float* fc_b   = (const float*)d_in[11];
  float* outp = (float*)d_out;

  const size_t szXGc = (size_t)BATCH * TCH * G4;     // floats per XG chunk buffer
  const size_t szH   = (size_t)BATCH * S_LEN * HDIM;
  const int    nWih  = (NLAYER - 1) * G4 * HDIM;
  const size_t nWF   = (size_t)NLAYER * 16 * 16 * 64 * 8;  // shorts

  const size_t fixed = (2 * szH + (size_t)NLAYER * BATCH * HDIM) * 4
                     + (size_t)nWih * 2 * 2 + nWF * 2;
  const size_t need_diag = fixed + (size_t)NCH * szXGc * 4;
  const size_t need_seq  = fixed + szXGc * 4;
  const bool diag = (ws_size >= need_diag);
  if (!diag && ws_size < need_seq) return;  // ws too small: fail visibly

  char* p = (char*)d_ws;
  float* XG = (float*)p;  p += (diag ? NCH : 1) * szXGc * 4;
  float* H0 = (float*)p;  p += szH * 4;
  float* H1 = (float*)p;  p += szH * 4;
  float* cst = (float*)p; p += (size_t)NLAYER * BATCH * HDIM * 4;
  unsigned short* Whi = (unsigned short*)p; p += (size_t)nWih * 2;
  unsigned short* Wlo = (unsigned short*)p; p += (size_t)nWih * 2;
  unsigned short* WF  = (unsigned short*)p; p += nWF * 2;
  float* lg = XG;                                   // XG[0] dead before attention
  const size_t xgStride = diag ? szXGc : 0;

  split_w<<<(nWih + 255) / 256, 256, 0, stream>>>(w_ih, Whi, Wlo, nWih);
  whh_prep<<<(NLAYER * 16 * 16 * 64 + 255) / 256, 256, 0, stream>>>(w_hh, WF);

  if (diag) {
    // Layer-0 XG for all chunks upfront (no dependencies).
    gemm_xg_f32<27><<<dim3(BATCH * TCH / 64, 8, NCH), 256, 0, stream>>>(
        x, w_ih0, b_ih, b_hh, XG, xgStride, 0);
    for (int s = 0; s <= NLAYER + NCH - 2; ++s) {
      int lminS = (s - (NCH - 1) > 0) ? s - (NCH - 1) : 0;
      int lmaxS = (s < NLAYER - 1) ? s : NLAYER - 1;
      scan_mfma<<<dim3(NBLK, lmaxS - lminS + 1), 1024, 0, stream>>>(
          XG, xgStride, WF, H0, H1, cst, s, lminS);
      int s2 = s + 1;
      int l2min = (s2 - (NCH - 1) > 1) ? s2 - (NCH - 1) : 1;
      int l2max = (s2 < NLAYER - 1) ? s2 : NLAYER - 1;
      if (l2min <= l2max)
        gemm_mfma_st<<<dim3(BATCH * TCH / 64, 8, l2max - l2min + 1), 256, 0, stream>>>(
            H0, H1, Whi, Wlo, b_ih, b_hh, XG, xgStride, s2, l2min);
    }
  } else {
    for (int l = 0; l < NLAYER; ++l) {
      for (int ch = 0; ch < NCH; ++ch) {
        if (l == 0)
          gemm_xg_f32<27><<<dim3(BATCH * TCH / 64, 8, 1), 256, 0, stream>>>(
              x, w_ih0, b_ih, b_hh, XG, 0, ch * TCH);
        else
          gemm_mfma_st<<<dim3(BATCH * TCH / 64, 8, 1), 256, 0, stream>>>(
              H0, H1, Whi, Wlo, b_ih, b_hh, XG, 0, l + ch, l);
        scan_mfma<<<dim3(NBLK, 1), 1024, 0, stream>>>(XG, 0, WF, H0, H1, cst, l + ch, l);
      }
    }
  }

  const float* Hlast = H1;  // layer 9 (odd) writes H1
  attn1<<<dim3(BATCH, 4), 128, 0, stream>>>(Hlast, attn_w, attn_b, v_w, v_b, lg);
  attn2<<<BATCH, 128, 0, stream>>>(Hlast, lg, fc_w, fc_b, outp);
}

// Round 8
// 3065.594 us; speedup vs baseline: 6.2711x; 3.7272x over previous
//
#include <hip/hip_runtime.h>
#include <cstdint>
#include <cstddef>

#define S_LEN 512
#define HDIM  128
#define G4    512
#define BATCH 256
#define NLAYER 10
#define ROWS  16              // batch rows per scan block (MFMA 16x16 A-rows)
#define NBLK  (BATCH / ROWS)  // 16
#define RING  10              // live XG chunks never exceed NLAYER = 10

typedef float f32x4 __attribute__((ext_vector_type(4)));
typedef short short8 __attribute__((ext_vector_type(8)));

__device__ __forceinline__ float fsig(float x) {
  return __builtin_amdgcn_rcpf(1.0f + __expf(-x));
}
__device__ __forceinline__ float ftanh(float x) {
  return fmaf(2.0f, __builtin_amdgcn_rcpf(1.0f + __expf(-2.0f * x)), -1.0f);
}
__device__ __forceinline__ unsigned short bf16_rne(float x) {
  unsigned int u = __float_as_uint(x);
  unsigned int r = (u + 0x7fffu + ((u >> 16) & 1u)) >> 16;
  return (unsigned short)r;
}
__device__ __forceinline__ float bf16_to_f(unsigned short h) {
  return __uint_as_float(((unsigned int)h) << 16);
}

// ---------------------------------------------------------------------------
// Split fp32 weights into (hi, lo) bf16 pair: x ~= hi + lo.
// ---------------------------------------------------------------------------
__global__ void split_w(const float* __restrict__ W, unsigned short* __restrict__ hi,
                        unsigned short* __restrict__ lo, int n)
{
  int i = blockIdx.x * 256 + threadIdx.x;
  if (i < n) {
    float x = W[i];
    unsigned short h = bf16_rne(x);
    hi[i] = h;
    lo[i] = bf16_rne(x - bf16_to_f(h));
  }
}

// ---------------------------------------------------------------------------
// Pre-arrange split Whh into MFMA B-fragment-linear order (round-7, verified).
// ---------------------------------------------------------------------------
__global__ __launch_bounds__(256)
void whh_prep(const float* __restrict__ Whh, unsigned short* __restrict__ WF)
{
  int idx = blockIdx.x * 256 + threadIdx.x;   // [0, NLAYER*16*16*64)
  if (idx >= NLAYER * 16 * 16 * 64) return;
  int ln = idx & 63;
  int f  = (idx >> 6) & 15;
  int w  = (idx >> 10) & 15;
  int l  = idx >> 14;
  int ct = f >> 3, ks = (f >> 1) & 3, hl = f & 1;
  int col = w * 32 + ct * 16 + (ln & 15);
  int k0  = ks * 32 + (ln >> 4) * 8;
  const float* src = Whh + ((size_t)l * G4 + col) * HDIM + k0;
  unsigned short out[8];
  #pragma unroll
  for (int j = 0; j < 8; ++j) {
    float x = src[j];
    unsigned short h = bf16_rne(x);
    out[j] = hl ? bf16_rne(x - bf16_to_f(h)) : h;
  }
  *(short8*)&WF[(size_t)idx * 8] = *(short8*)out;
}

// ---------------------------------------------------------------------------
// Layer-0 input GEMM (K=27), fp32 VALU. One chunk per launch (JIT in ring).
// ---------------------------------------------------------------------------
template<int K>
__global__ __launch_bounds__(256, 4)
void gemm_xg_f32(const float* __restrict__ A, const float* __restrict__ W,
                 const float* __restrict__ bih, const float* __restrict__ bhh,
                 float* __restrict__ XGring, int tchShift, int chunk)
{
  const int TCHr = 1 << tchShift;
  const int t0 = chunk << tchShift;
  float* __restrict__ XG = XGring + (size_t)(chunk % RING) * (((size_t)BATCH * G4) << tchShift);
  constexpr int BK  = (K < 64) ? K : 64;
  constexpr int NKC = K / BK;
  __shared__ float As[BK][68];
  __shared__ float Bs[BK][68];
  const int tid = threadIdx.x;
  const int tx = tid & 15;
  const int ty = tid >> 4;
  const int rowBase = blockIdx.x * 64;
  const int colBase = blockIdx.y * 64;
  float acc[4][4] = {{0.f,0.f,0.f,0.f},{0.f,0.f,0.f,0.f},{0.f,0.f,0.f,0.f},{0.f,0.f,0.f,0.f}};

  for (int kc = 0; kc < NKC; ++kc) {
    const int kbase = kc * BK;
    for (int idx = tid; idx < 64 * BK; idx += 256) {
      int rr = idx / BK;
      int k  = idx - rr * BK;
      int r  = rowBase + rr;
      int bb = r >> tchShift;
      int tt = r & (TCHr - 1);
      As[k][rr] = A[(size_t)(bb * S_LEN + t0 + tt) * K + kbase + k];
    }
    for (int idx = tid; idx < 64 * BK; idx += 256) {
      int cc = idx / BK;
      int k  = idx - cc * BK;
      Bs[k][cc] = W[(size_t)(colBase + cc) * K + kbase + k];
    }
    __syncthreads();
    #pragma unroll 8
    for (int k = 0; k < BK; ++k) {
      const float4 av = *(const float4*)&As[k][ty * 4];
      const float4 bv = *(const float4*)&Bs[k][tx * 4];
      float a_[4] = {av.x, av.y, av.z, av.w};
      float b_[4] = {bv.x, bv.y, bv.z, bv.w};
      #pragma unroll
      for (int i = 0; i < 4; ++i) {
        #pragma unroll
        for (int jj = 0; jj < 4; ++jj)
          acc[i][jj] = fmaf(a_[i], b_[jj], acc[i][jj]);
      }
    }
    __syncthreads();
  }

  const int col0 = colBase + tx * 4;
  const float4 bi4 = *(const float4*)&bih[col0];
  const float4 bh4 = *(const float4*)&bhh[col0];
  const float b0 = bi4.x + bh4.x, b1 = bi4.y + bh4.y, b2 = bi4.z + bh4.z, b3 = bi4.w + bh4.w;
  #pragma unroll
  for (int i = 0; i < 4; ++i) {
    int r = rowBase + ty * 4 + i;
    float4 o;
    o.x = acc[i][0] + b0; o.y = acc[i][1] + b1; o.z = acc[i][2] + b2; o.w = acc[i][3] + b3;
    *(float4*)&XG[(size_t)r * G4 + col0] = o;
  }
}

// ---------------------------------------------------------------------------
// Split-bf16 MFMA input GEMM (layers 1..9), B staged in LDS (round-6 body).
// ---------------------------------------------------------------------------
__global__ __launch_bounds__(256, 2)
void gemm_mfma_st(const float* __restrict__ H0, const float* __restrict__ H1,
                  const unsigned short* __restrict__ WhiAll,
                  const unsigned short* __restrict__ WloAll,
                  const float* __restrict__ bihAll, const float* __restrict__ bhhAll,
                  float* __restrict__ XGring, int tchShift, int s, int lmin)
{
  __shared__ unsigned short Ahi[64][136];
  __shared__ unsigned short Alo[64][136];
  __shared__ unsigned short Bhi[64][72];
  __shared__ unsigned short Blo[64][72];
  const int l = lmin + blockIdx.z;
  const int c = s - l;
  const int TCHr = 1 << tchShift;
  const int t0 = c << tchShift;
  const float* __restrict__ A = ((l - 1) & 1) ? H1 : H0;
  const unsigned short* __restrict__ Whi = WhiAll + (size_t)(l - 1) * G4 * HDIM;
  const unsigned short* __restrict__ Wlo = WloAll + (size_t)(l - 1) * G4 * HDIM;
  const float* __restrict__ bih = bihAll + l * G4;
  const float* __restrict__ bhh = bhhAll + l * G4;
  float* __restrict__ XG = XGring + (size_t)(c % RING) * (((size_t)BATCH * G4) << tchShift);

  const int tid = threadIdx.x;
  const int rowBase = blockIdx.x * 64;
  const int colBase = blockIdx.y * 64;

  #pragma unroll
  for (int it = 0; it < 4; ++it) {
    int idx = tid + it * 256;
    int rr  = idx >> 4;
    int kg  = (idx & 15) * 8;
    int r   = rowBase + rr;
    int bb  = r >> tchShift;
    int tt  = r & (TCHr - 1);
    const float* ap = &A[(size_t)(bb * S_LEN + t0 + tt) * HDIM + kg];
    float4 v0 = *(const float4*)ap;
    float4 v1 = *(const float4*)(ap + 4);
    float xs[8] = {v0.x, v0.y, v0.z, v0.w, v1.x, v1.y, v1.z, v1.w};
    unsigned short h[8], l8[8];
    #pragma unroll
    for (int j = 0; j < 8; ++j) {
      h[j]  = bf16_rne(xs[j]);
      l8[j] = bf16_rne(xs[j] - bf16_to_f(h[j]));
    }
    *(short8*)&Ahi[rr][kg] = *(short8*)h;
    *(short8*)&Alo[rr][kg] = *(short8*)l8;
  }

  const int w    = tid >> 6;
  const int ln   = tid & 63;
  const int fr   = ln & 15;
  const int kgrp = (ln >> 4) * 8;

  f32x4 acc[4] = {};
  #pragma unroll
  for (int kh = 0; kh < 2; ++kh) {
    __syncthreads();
    #pragma unroll
    for (int it = 0; it < 2; ++it) {
      int idx = tid + it * 256;
      int cc  = idx >> 3;
      int kg  = (idx & 7) * 8;
      *(short8*)&Bhi[cc][kg] = *(const short8*)&Whi[(size_t)(colBase + cc) * HDIM + kh * 64 + kg];
      *(short8*)&Blo[cc][kg] = *(const short8*)&Wlo[(size_t)(colBase + cc) * HDIM + kh * 64 + kg];
    }
    __syncthreads();
    #pragma unroll
    for (int ks = 0; ks < 2; ++ks) {
      const int k0 = kh * 64 + ks * 32 + kgrp;
      const int kb = ks * 32 + kgrp;
      short8 ah = *(const short8*)&Ahi[(w << 4) + fr][k0];
      short8 al = *(const short8*)&Alo[(w << 4) + fr][k0];
      #pragma unroll
      for (int nt = 0; nt < 4; ++nt) {
        short8 bh = *(const short8*)&Bhi[nt * 16 + fr][kb];
        short8 bl = *(const short8*)&Blo[nt * 16 + fr][kb];
        acc[nt] = __builtin_amdgcn_mfma_f32_16x16x32_bf16(ah, bh, acc[nt], 0, 0, 0);
        acc[nt] = __builtin_amdgcn_mfma_f32_16x16x32_bf16(ah, bl, acc[nt], 0, 0, 0);
        acc[nt] = __builtin_amdgcn_mfma_f32_16x16x32_bf16(al, bh, acc[nt], 0, 0, 0);
      }
    }
  }

  #pragma unroll
  for (int nt = 0; nt < 4; ++nt) {
    const int col = colBase + nt * 16 + fr;
    const float bsum = bih[col] + bhh[col];
    #pragma unroll
    for (int j = 0; j < 4; ++j) {
      int r = rowBase + (w << 4) + ((ln >> 4) << 2) + j;
      XG[(size_t)r * G4 + col] = acc[nt][j] + bsum;
    }
  }
}

// ---------------------------------------------------------------------------
// MFMA LSTM scan (round-7 body, correctness-verified; now runtime TCH + ring).
// Block = 16 batch rows of pair (l, ch); 1024 threads; grid (16, npairs).
// ---------------------------------------------------------------------------
__global__ __launch_bounds__(1024, 4)
void scan_mfma(const float* __restrict__ XGring, int tchShift,
               const unsigned short* __restrict__ WF,
               float* __restrict__ H0, float* __restrict__ H1,
               float* __restrict__ cstAll, int s, int lmin)
{
  const int l  = lmin + blockIdx.y;
  const int ch = s - l;
  const int TCHr = 1 << tchShift;
  const int t0 = ch << tchShift;
  const size_t rowStride = (size_t)G4 << tchShift;   // floats per batch row in XG
  const float* __restrict__ XG = XGring + (size_t)(ch % RING) * ((size_t)BATCH * rowStride);
  float* __restrict__ Hout = (l & 1) ? H1 : H0;
  float* __restrict__ cst  = cstAll + (size_t)l * BATCH * HDIM;
  const int B0  = blockIdx.x * ROWS;
  const int tid = threadIdx.x;
  const int w   = tid >> 6;
  const int ln  = tid & 63;
  const int lr  = ln & 15;
  const int lk  = ln >> 4;

  __shared__ unsigned short hA[2 * ROWS * HDIM];  // [hl][row][k], swizzled
  __shared__ float pp[ROWS * G4];                 // pre-acts, swizzled

  // B fragments into registers (16 coalesced b128 loads)
  short8 bf[16];
  {
    const unsigned short* wfp = WF + (((size_t)l * 16 + w) * 16) * 512 + (size_t)ln * 8;
    #pragma unroll
    for (int f = 0; f < 16; ++f) bf[f] = *(const short8*)(wfp + (size_t)f * 512);
    #pragma unroll
    for (int f = 0; f < 16; ++f) asm("" : "+v"(bf[f]));
  }

  const int grow0 = tid >> 7;        // 0..7
  const int grow1 = grow0 + 8;
  const int ghid  = tid & 127;
  float c0 = 0.f, c1 = 0.f;
  {
    float h0v = 0.f, h1v = 0.f;
    if (t0 > 0) {
      h0v = Hout[((size_t)(B0 + grow0) * S_LEN + (t0 - 1)) * HDIM + ghid];
      h1v = Hout[((size_t)(B0 + grow1) * S_LEN + (t0 - 1)) * HDIM + ghid];
      c0 = cst[(B0 + grow0) * HDIM + ghid];
      c1 = cst[(B0 + grow1) * HDIM + ghid];
    }
    unsigned short hi0 = bf16_rne(h0v);
    unsigned short lo0 = bf16_rne(h0v - bf16_to_f(hi0));
    unsigned short hi1 = bf16_rne(h1v);
    unsigned short lo1 = bf16_rne(h1v - bf16_to_f(hi1));
    int by0 = (grow0 * 256 + ghid * 2) ^ ((grow0 & 7) << 4);
    int by1 = (grow1 * 256 + ghid * 2) ^ ((grow1 & 7) << 4);
    *(unsigned short*)((char*)hA + by0) = hi0;
    *(unsigned short*)((char*)hA + 4096 + by0) = lo0;
    *(unsigned short*)((char*)hA + by1) = hi1;
    *(unsigned short*)((char*)hA + 4096 + by1) = lo1;
  }
  __syncthreads();

  const float* xgl = XG + (size_t)(B0 + lk * 4) * rowStride + w * 32 + lr;
  float* hout0 = Hout + ((size_t)(B0 + grow0) * S_LEN + t0) * HDIM + ghid;
  float* hout1 = Hout + ((size_t)(B0 + grow1) * S_LEN + t0) * HDIM + ghid;

  for (int tt = 0; tt < TCHr; ++tt) {
    float xgv[8];
    #pragma unroll
    for (int ct = 0; ct < 2; ++ct)
      #pragma unroll
      for (int j = 0; j < 4; ++j)
        xgv[ct * 4 + j] = xgl[(size_t)j * rowStride + ct * 16];

    f32x4 acc0 = {0.f, 0.f, 0.f, 0.f}, acc1 = {0.f, 0.f, 0.f, 0.f};
    #pragma unroll
    for (int ks = 0; ks < 4; ++ks) {
      const int by = (lr * 256 + ks * 64 + lk * 16) ^ ((lr & 7) << 4);
      short8 ah = *(const short8*)((const char*)hA + by);
      short8 al = *(const short8*)((const char*)hA + 4096 + by);
      acc0 = __builtin_amdgcn_mfma_f32_16x16x32_bf16(ah, bf[(ks << 1) | 0], acc0, 0, 0, 0);
      acc0 = __builtin_amdgcn_mfma_f32_16x16x32_bf16(ah, bf[(ks << 1) | 1], acc0, 0, 0, 0);
      acc0 = __builtin_amdgcn_mfma_f32_16x16x32_bf16(al, bf[(ks << 1) | 0], acc0, 0, 0, 0);
      acc1 = __builtin_amdgcn_mfma_f32_16x16x32_bf16(ah, bf[8 | (ks << 1) | 0], acc1, 0, 0, 0);
      acc1 = __builtin_amdgcn_mfma_f32_16x16x32_bf16(ah, bf[8 | (ks << 1) | 1], acc1, 0, 0, 0);
      acc1 = __builtin_amdgcn_mfma_f32_16x16x32_bf16(al, bf[8 | (ks << 1) | 0], acc1, 0, 0, 0);
    }

    #pragma unroll
    for (int j = 0; j < 4; ++j) {
      int r16 = lk * 4 + j;
      int colA = w * 32 + lr;
      int byA = (r16 * 2048 + colA * 4) ^ ((r16 & 3) << 5);
      *(float*)((char*)pp + byA) = acc0[j] + xgv[j];
      int colB = colA + 16;
      int byB = (r16 * 2048 + colB * 4) ^ ((r16 & 3) << 5);
      *(float*)((char*)pp + byB) = acc1[j] + xgv[4 + j];
    }
    __syncthreads();

    {
      int b0 = grow0 * 2048, x0 = (grow0 & 3) << 5;
      float pi = *(const float*)((const char*)pp + ((b0 + (ghid)       * 4) ^ x0));
      float pf = *(const float*)((const char*)pp + ((b0 + (128 + ghid) * 4) ^ x0));
      float pg = *(const float*)((const char*)pp + ((b0 + (256 + ghid) * 4) ^ x0));
      float po = *(const float*)((const char*)pp + ((b0 + (384 + ghid) * 4) ^ x0));
      float gi = fsig(pi), gf = fsig(pf), gg = ftanh(pg), go = fsig(po);
      c0 = fmaf(gf, c0, gi * gg);
      float h0 = go * ftanh(c0);

      int b1 = grow1 * 2048, x1 = (grow1 & 3) << 5;
      float qi = *(const float*)((const char*)pp + ((b1 + (ghid)       * 4) ^ x1));
      float qf = *(const float*)((const char*)pp + ((b1 + (128 + ghid) * 4) ^ x1));
      float qg = *(const float*)((const char*)pp + ((b1 + (256 + ghid) * 4) ^ x1));
      float qo = *(const float*)((const char*)pp + ((b1 + (384 + ghid) * 4) ^ x1));
      float hi_ = fsig(qi), hf = fsig(qf), hg = ftanh(qg), ho = fsig(qo);
      c1 = fmaf(hf, c1, hi_ * hg);
      float h1 = ho * ftanh(c1);

      hout0[0] = h0;
      hout1[0] = h1;
      unsigned short s0 = bf16_rne(h0);
      unsigned short t0b = bf16_rne(h0 - bf16_to_f(s0));
      unsigned short s1 = bf16_rne(h1);
      unsigned short t1b = bf16_rne(h1 - bf16_to_f(s1));
      int by0 = (grow0 * 256 + ghid * 2) ^ ((grow0 & 7) << 4);
      int by1 = (grow1 * 256 + ghid * 2) ^ ((grow1 & 7) << 4);
      *(unsigned short*)((char*)hA + by0) = s0;
      *(unsigned short*)((char*)hA + 4096 + by0) = t0b;
      *(unsigned short*)((char*)hA + by1) = s1;
      *(unsigned short*)((char*)hA + 4096 + by1) = t1b;
    }
    __syncthreads();
    xgl += G4;
    hout0 += HDIM;
    hout1 += HDIM;
  }
  cst[(B0 + grow0) * HDIM + ghid] = c0;
  cst[(B0 + grow1) * HDIM + ghid] = c1;
}

// ---------------------------------------------------------------------------
// Attention pass 1 (unchanged)
// ---------------------------------------------------------------------------
__global__ __launch_bounds__(128)
void attn1(const float* __restrict__ Hs, const float* __restrict__ attn_w,
           const float* __restrict__ attn_b, const float* __restrict__ v_w,
           const float* __restrict__ v_b, float* __restrict__ logits)
{
  const int b  = blockIdx.x;
  const int tc = blockIdx.y;
  const int j  = threadIdx.x;
  float wreg[HDIM];
  {
    const float4* wr = (const float4*)(attn_w + (size_t)j * HDIM);
    #pragma unroll
    for (int kk = 0; kk < 32; ++kk) {
      float4 v = wr[kk];
      wreg[4*kk+0] = v.x; wreg[4*kk+1] = v.y; wreg[4*kk+2] = v.z; wreg[4*kk+3] = v.w;
    }
  }
  const float ab = attn_b[j];
  const float vw = v_w[j];
  const float vb = v_b[0];
  __shared__ float outs[16][HDIM];
  __shared__ float red[2];
  for (int t8 = 0; t8 < 8; ++t8) {
    const int tbase = tc * 128 + t8 * 16;
    for (int idx = j; idx < 16 * HDIM; idx += 128) {
      int rr = idx >> 7;
      int k  = idx & 127;
      outs[rr][k] = Hs[(size_t)(b * S_LEN + tbase + rr) * HDIM + k];
    }
    __syncthreads();
    for (int rr = 0; rr < 16; ++rr) {
      const float4* o4 = (const float4*)outs[rr];
      float a0 = 0.f, a1 = 0.f, a2 = 0.f, a3 = 0.f;
      #pragma unroll
      for (int kk = 0; kk < 32; ++kk) {
        float4 hv = o4[kk];
        a0 = fmaf(wreg[4*kk+0], hv.x, a0);
        a1 = fmaf(wreg[4*kk+1], hv.y, a1);
        a2 = fmaf(wreg[4*kk+2], hv.z, a2);
        a3 = fmaf(wreg[4*kk+3], hv.w, a3);
      }
      float s = ftanh(((a0 + a1) + (a2 + a3)) + ab) * vw;
      #pragma unroll
      for (int off = 1; off < 64; off <<= 1) s += __shfl_xor(s, off);
      if ((j & 63) == 0) red[j >> 6] = s;
      __syncthreads();
      if (j == 0) logits[b * S_LEN + tbase + rr] = red[0] + red[1] + vb;
      __syncthreads();
    }
  }
}

// ---------------------------------------------------------------------------
// Attention pass 2 (unchanged)
// ---------------------------------------------------------------------------
__global__ __launch_bounds__(128)
void attn2(const float* __restrict__ Hs, const float* __restrict__ logits,
           const float* __restrict__ fc_w, const float* __restrict__ fc_b,
           float* __restrict__ outp)
{
  const int b   = blockIdx.x;
  const int tid = threadIdx.x;
  __shared__ float pbuf[S_LEN];
  __shared__ float red[4];
  __shared__ float ctx_s[HDIM];
  float l0 = logits[b * S_LEN + tid];
  float l1 = logits[b * S_LEN + 128 + tid];
  float l2 = logits[b * S_LEN + 256 + tid];
  float l3 = logits[b * S_LEN + 384 + tid];
  float m = fmaxf(fmaxf(l0, l1), fmaxf(l2, l3));
  #pragma unroll
  for (int off = 1; off < 64; off <<= 1) m = fmaxf(m, __shfl_xor(m, off));
  if ((tid & 63) == 0) red[tid >> 6] = m;
  __syncthreads();
  m = fmaxf(red[0], red[1]);
  float p0 = __expf(l0 - m), p1 = __expf(l1 - m), p2 = __expf(l2 - m), p3 = __expf(l3 - m);
  pbuf[tid] = p0; pbuf[tid + 128] = p1; pbuf[tid + 256] = p2; pbuf[tid + 384] = p3;
  float sum = (p0 + p1) + (p2 + p3);
  #pragma unroll
  for (int off = 1; off < 64; off <<= 1) sum += __shfl_xor(sum, off);
  if ((tid & 63) == 0) red[2 + (tid >> 6)] = sum;
  __syncthreads();
  const float sinv = 1.0f / (red[2] + red[3]);
  float acc = 0.f;
  const float* hp = Hs + (size_t)b * S_LEN * HDIM + tid;
  #pragma unroll 4
  for (int t = 0; t < S_LEN; ++t) acc = fmaf(pbuf[t], hp[(size_t)t * HDIM], acc);
  ctx_s[tid] = acc * sinv;
  __syncthreads();
  if (tid < 7) {
    float a = fc_b[tid];
    const float* fw = fc_w + tid * HDIM;
    #pragma unroll 8
    for (int k = 0; k < HDIM; ++k) a = fmaf(ctx_s[k], fw[k], a);
    outp[b * 7 + tid] = a;
  }
}

// ---------------------------------------------------------------------------
extern "C" void kernel_launch(void* const* d_in, const int* in_sizes, int n_in,
                              void* d_out, int out_size, void* d_ws, size_t ws_size,
                              hipStream_t stream)
{
  const float* x      = (const float*)d_in[0];
  const float* w_ih0  = (const float*)d_in[1];
  const float* w_ih   = (const float*)d_in[2];
  const float* w_hh   = (const float*)d_in[3];
  const float* b_ih   = (const float*)d_in[4];
  const float* b_hh   = (const float*)d_in[5];
  const float* attn_w = (const float*)d_in[6];
  const float* attn_b = (const float*)d_in[7];
  const float* v_w    = (const float*)d_in[8];
  const float* v_b    = (const float*)d_in[9];
  const float* fc_w   = (const float*)d_in[10];
  const float* fc_b   = (const float*)d_in[11];
  float* outp = (float*)d_out;

  const size_t szH_b  = (size_t)BATCH * S_LEN * HDIM * 4;          // 67 MB
  const int    nWih   = (NLAYER - 1) * G4 * HDIM;
  const size_t nWF    = (size_t)NLAYER * 16 * 16 * 64 * 8;         // shorts
  const size_t fixed  = 2 * szH_b + (size_t)NLAYER * BATCH * HDIM * 4
                      + (size_t)nWih * 2 * 2 + nWF * 2;            // ~140.5 MB

  // Pick the largest power-of-two chunk whose 10-deep XG ring fits.
  int tchShift = -1;
  for (int sh = 5; sh >= 3; --sh) {   // TCH = 32, 16, 8
    size_t ringBytes = (size_t)RING * (((size_t)BATCH * G4) << sh) * 4;
    if (ws_size >= fixed + ringBytes) { tchShift = sh; break; }
  }
  if (tchShift < 0) return;           // ws too small (cannot happen per round-5 evidence)
  const int TCHr = 1 << tchShift;
  const int NCHr = S_LEN >> tchShift;

  char* p = (char*)d_ws;
  float* XGring = (float*)p; p += (size_t)RING * (((size_t)BATCH * G4) << tchShift) * 4;
  float* H0  = (float*)p; p += szH_b;
  float* H1  = (float*)p; p += szH_b;
  float* cst = (float*)p; p += (size_t)NLAYER * BATCH * HDIM * 4;
  unsigned short* Whi = (unsigned short*)p; p += (size_t)nWih * 2;
  unsigned short* Wlo = (unsigned short*)p; p += (size_t)nWih * 2;
  unsigned short* WF  = (unsigned short*)p; p += nWF * 2;
  float* lg = XGring;   // ring buffer 0 is dead before attention

  split_w<<<(nWih + 255) / 256, 256, 0, stream>>>(w_ih, Whi, Wlo, nWih);
  whh_prep<<<(NLAYER * 16 * 16 * 64 + 255) / 256, 256, 0, stream>>>(w_hh, WF);

  const int gemmGx = (BATCH << tchShift) / 64;
  // Full wavefront: stage s holds pairs (l, c=s-l); ring slot = c % 10.
  for (int s = 0; s <= NLAYER + NCHr - 2; ++s) {
    int lmin = (s - (NCHr - 1) > 0) ? s - (NCHr - 1) : 0;
    int lmax = (s < NLAYER - 1) ? s : NLAYER - 1;
    if (s < NCHr)    // JIT layer-0 projection for chunk c = s
      gemm_xg_f32<27><<<dim3(gemmGx, 8), 256, 0, stream>>>(
          x, w_ih0, b_ih, b_hh, XGring, tchShift, s);
    int gmin = (lmin > 1) ? lmin : 1;
    if (gmin <= lmax)
      gemm_mfma_st<<<dim3(gemmGx, 8, lmax - gmin + 1), 256, 0, stream>>>(
          H0, H1, Whi, Wlo, b_ih, b_hh, XGring, tchShift, s, gmin);
    scan_mfma<<<dim3(NBLK, lmax - lmin + 1), 1024, 0, stream>>>(
        XGring, tchShift, WF, H0, H1, cst, s, lmin);
  }

  const float* Hlast = H1;  // layer 9 (odd) writes H1
  attn1<<<dim3(BATCH, 4), 128, 0, stream>>>(Hlast, attn_w, attn_b, v_w, v_b, lg);
  attn2<<<BATCH, 128, 0, stream>>>(Hlast, lg, fc_w, fc_b, outp);
}